// Round 3
// baseline (667.095 us; speedup 1.0000x reference)
//
#include <hip/hip_runtime.h>
#include <hip/hip_bf16.h>
#include <math.h>

#define B_ 8
#define N_ 384
#define F_ 64
#define H_ 128
#define LN_EPS 1e-5f
#define NCHUNK 72          // N_*N_ / 2048

// -------------------- setup kernels --------------------

// W2p[k][n] = 0.5 * sum_f vW2[k,f] * sW1[f,n]   (128x128)
__global__ void k_prep_w2p(const float* __restrict__ vW2, const float* __restrict__ sW1,
                           float* __restrict__ W2p) {
    int idx = blockIdx.x * 256 + threadIdx.x;   // 0..16383
    int k = idx >> 7, n = idx & 127;
    float acc = 0.f;
#pragma unroll
    for (int f = 0; f < F_; ++f) acc = fmaf(vW2[k * F_ + f], sW1[f * H_ + n], acc);
    W2p[idx] = 0.5f * acc;
}

// t[row][n] = sum_f (0.25*(in[row,f]+vb2[f])) * sW1[f,n] + 0.5*sb1[n]
__global__ void k_prep_t(const float* __restrict__ inp, const float* __restrict__ sW1,
                         const float* __restrict__ vb2, const float* __restrict__ sb1,
                         float* __restrict__ t) {
    int row = blockIdx.x;
    int n = threadIdx.x;
    float acc = 0.f;
#pragma unroll
    for (int f = 0; f < F_; ++f)
        acc = fmaf(0.25f * (inp[row * F_ + f] + vb2[f]), sW1[f * H_ + n], acc);
    t[row * H_ + n] = acc + 0.5f * sb1[n];
}

// -------------------- phase 1: scores --------------------
// Block: 8x8 pair tile. Phase A: relu(LN(invariants@vW1+vb1)) -> LDS (transposed).
// Phase B: [64x128] @ W'[128x128] GEMM (W' staged to LDS in 32-row chunks).
// Phase C: + t_i + t_j, relu, dot sW2 -> score written to d_out att region.
__global__ __launch_bounds__(256) void k_scores(
    const float* __restrict__ pos, const float* __restrict__ vW1,
    const float* __restrict__ vb1, const float* __restrict__ vg,
    const float* __restrict__ vbeta, const float* __restrict__ W2p,
    const float* __restrict__ t, const float* __restrict__ sW2,
    const float* __restrict__ sb2, float* __restrict__ scores) {
    __shared__ float rht[128 * 72];   // transposed relu_h: [k][pair], stride 72
    __shared__ float wl[32 * 128];    // W' chunk

    const int tid = threadIdx.x;
    const int b = blockIdx.z;
    const int i0 = blockIdx.y * 8, j0 = blockIdx.x * 8;

    // ---- Phase A: 4 threads per pair, each owns 32 of 128 dims ----
    {
        const int p = tid >> 2, l = tid & 3;
        const int i = i0 + (p >> 3), j = j0 + (p & 7);
        const float* pi = pos + (size_t)(b * N_ + i) * 3;
        const float* pj = pos + (size_t)(b * N_ + j) * 3;
        float ax = pi[0], ay = pi[1], az = pi[2];
        float bx = pj[0], by = pj[1], bz = pj[2];
        float dotv = ax * bx + ay * by + az * bz;
        float cx = ay * bz - az * by;
        float cy = az * bx - ax * bz;
        float cz = ax * by - ay * bx;
        float cn = sqrtf(cx * cx + cy * cy + cz * cz);

        float h[32];
        float s1 = 0.f, s2 = 0.f;
        const int d0 = l * 32;
#pragma unroll
        for (int dd = 0; dd < 32; ++dd) {
            int d = d0 + dd;
            float v = fmaf(dotv, vW1[d], fmaf(cn, vW1[H_ + d], vb1[d]));
            h[dd] = v;
            s1 += v;
            s2 = fmaf(v, v, s2);
        }
        s1 += __shfl_xor(s1, 1); s1 += __shfl_xor(s1, 2);
        s2 += __shfl_xor(s2, 1); s2 += __shfl_xor(s2, 2);
        float mu = s1 * (1.f / 128.f);
        float var = s2 * (1.f / 128.f) - mu * mu;
        float rstd = rsqrtf(var + LN_EPS);
#pragma unroll
        for (int dd = 0; dd < 32; ++dd) {
            int d = d0 + dd;
            float v = fmaf((h[dd] - mu) * rstd, vg[d], vbeta[d]);
            rht[d * 72 + p] = fmaxf(v, 0.f);
        }
    }
    __syncthreads();

    // ---- Phase B: GEMM. thread (pp = tid>>5, nn = tid&31): 8 pairs x 4 cols ----
    const int nn = tid & 31, pp = tid >> 5;
    float acc[8][4];
#pragma unroll
    for (int q = 0; q < 8; ++q) {
        acc[q][0] = 0.f; acc[q][1] = 0.f; acc[q][2] = 0.f; acc[q][3] = 0.f;
    }

    for (int kc = 0; kc < 4; ++kc) {
        // stage 32 rows of W' into LDS
#pragma unroll
        for (int s = 0; s < 4; ++s) {
            int idx = tid + s * 256;            // float4 index, 0..1023
            int kk = idx >> 5, col = (idx & 31) * 4;
            *(float4*)(wl + kk * 128 + col) =
                *(const float4*)(W2p + (kc * 32 + kk) * 128 + col);
        }
        __syncthreads();
#pragma unroll 4
        for (int kk = 0; kk < 32; ++kk) {
            const int kb = kc * 32 + kk;
            float4 w = *(const float4*)(wl + kk * 128 + nn * 4);
            float4 r0 = *(const float4*)(rht + kb * 72 + pp * 8);
            float4 r1 = *(const float4*)(rht + kb * 72 + pp * 8 + 4);
            acc[0][0] = fmaf(r0.x, w.x, acc[0][0]); acc[0][1] = fmaf(r0.x, w.y, acc[0][1]);
            acc[0][2] = fmaf(r0.x, w.z, acc[0][2]); acc[0][3] = fmaf(r0.x, w.w, acc[0][3]);
            acc[1][0] = fmaf(r0.y, w.x, acc[1][0]); acc[1][1] = fmaf(r0.y, w.y, acc[1][1]);
            acc[1][2] = fmaf(r0.y, w.z, acc[1][2]); acc[1][3] = fmaf(r0.y, w.w, acc[1][3]);
            acc[2][0] = fmaf(r0.z, w.x, acc[2][0]); acc[2][1] = fmaf(r0.z, w.y, acc[2][1]);
            acc[2][2] = fmaf(r0.z, w.z, acc[2][2]); acc[2][3] = fmaf(r0.z, w.w, acc[2][3]);
            acc[3][0] = fmaf(r0.w, w.x, acc[3][0]); acc[3][1] = fmaf(r0.w, w.y, acc[3][1]);
            acc[3][2] = fmaf(r0.w, w.z, acc[3][2]); acc[3][3] = fmaf(r0.w, w.w, acc[3][3]);
            acc[4][0] = fmaf(r1.x, w.x, acc[4][0]); acc[4][1] = fmaf(r1.x, w.y, acc[4][1]);
            acc[4][2] = fmaf(r1.x, w.z, acc[4][2]); acc[4][3] = fmaf(r1.x, w.w, acc[4][3]);
            acc[5][0] = fmaf(r1.y, w.x, acc[5][0]); acc[5][1] = fmaf(r1.y, w.y, acc[5][1]);
            acc[5][2] = fmaf(r1.y, w.z, acc[5][2]); acc[5][3] = fmaf(r1.y, w.w, acc[5][3]);
            acc[6][0] = fmaf(r1.z, w.x, acc[6][0]); acc[6][1] = fmaf(r1.z, w.y, acc[6][1]);
            acc[6][2] = fmaf(r1.z, w.z, acc[6][2]); acc[6][3] = fmaf(r1.z, w.w, acc[6][3]);
            acc[7][0] = fmaf(r1.w, w.x, acc[7][0]); acc[7][1] = fmaf(r1.w, w.y, acc[7][1]);
            acc[7][2] = fmaf(r1.w, w.z, acc[7][2]); acc[7][3] = fmaf(r1.w, w.w, acc[7][3]);
        }
        __syncthreads();
    }

    // ---- Phase C: u += t_i + t_j, relu, dot sW2, half-wave reduce ----
    const int i = i0 + pp;
    float4 ti = *(const float4*)(t + (size_t)(b * N_ + i) * H_ + nn * 4);
    float4 sw2 = *(const float4*)(sW2 + nn * 4);
    float sb2v = sb2[0];
#pragma unroll
    for (int q = 0; q < 8; ++q) {
        int j = j0 + q;
        float4 tj = *(const float4*)(t + (size_t)(b * N_ + j) * H_ + nn * 4);
        float u0 = fmaxf(acc[q][0] + ti.x + tj.x, 0.f);
        float u1 = fmaxf(acc[q][1] + ti.y + tj.y, 0.f);
        float u2 = fmaxf(acc[q][2] + ti.z + tj.z, 0.f);
        float u3 = fmaxf(acc[q][3] + ti.w + tj.w, 0.f);
        float part = u0 * sw2.x + u1 * sw2.y + u2 * sw2.z + u3 * sw2.w;
#pragma unroll
        for (int m = 1; m < 32; m <<= 1) part += __shfl_xor(part, m);
        if (nn == 0) scores[(size_t)(b * N_ + i) * N_ + j] = part + sb2v;
    }
}

// -------------------- softmax reductions (deterministic trees) --------------------

__global__ void k_pmax(const float* __restrict__ scores, float* __restrict__ pmax) {
    int c = blockIdx.x, b = blockIdx.y;
    int tid = threadIdx.x;
    size_t base = (size_t)b * N_ * N_ + (size_t)c * 2048;
    float m = -1e30f;
#pragma unroll
    for (int s = 0; s < 8; ++s) m = fmaxf(m, scores[base + s * 256 + tid]);
    __shared__ float red[256];
    red[tid] = m;
    __syncthreads();
    for (int st = 128; st > 0; st >>= 1) {
        if (tid < st) red[tid] = fmaxf(red[tid], red[tid + st]);
        __syncthreads();
    }
    if (tid == 0) pmax[b * NCHUNK + c] = red[0];
}

__global__ void k_psum(const float* __restrict__ scores, const float* __restrict__ pmax,
                       float* __restrict__ psum) {
    int c = blockIdx.x, b = blockIdx.y;
    int tid = threadIdx.x;
    __shared__ float gm;
    __shared__ float red[256];
    if (tid == 0) {
        float m = -1e30f;
        for (int k = 0; k < NCHUNK; ++k) m = fmaxf(m, pmax[b * NCHUNK + k]);
        gm = m;
    }
    __syncthreads();
    size_t base = (size_t)b * N_ * N_ + (size_t)c * 2048;
    float s = 0.f;
#pragma unroll
    for (int k = 0; k < 8; ++k) s += expf(scores[base + k * 256 + tid] - gm);
    red[tid] = s;
    __syncthreads();
    for (int st = 128; st > 0; st >>= 1) {
        if (tid < st) red[tid] += red[tid + st];
        __syncthreads();
    }
    if (tid == 0) psum[b * NCHUNK + c] = red[0];
}

// normalize scores -> att in place (one block per (b,i) row)
__global__ void k_att(float* __restrict__ scores, const float* __restrict__ pmax,
                      const float* __restrict__ psum) {
    int i = blockIdx.x, b = blockIdx.y;
    int tid = threadIdx.x;   // 384
    __shared__ float gm, gs;
    if (tid == 0) {
        float m = -1e30f;
        for (int k = 0; k < NCHUNK; ++k) m = fmaxf(m, pmax[b * NCHUNK + k]);
        gm = m;
    } else if (tid == 1) {
        float s = 0.f;
        for (int k = 0; k < NCHUNK; ++k) s += psum[b * NCHUNK + k];
        gs = s;
    }
    __syncthreads();
    size_t idx = (size_t)(b * N_ + i) * N_ + tid;
    scores[idx] = expf(scores[idx] - gm) / gs;
}

// -------------------- phase 2: x --------------------
// One block per (b,i). Threads: (jsub = tid>>3 in 0..31, dg = tid&7).
// Recompute relu_h in fp32, accumulate accH = sum att*relu_h, accI = sum att*in_j, s = sum att.
// x = 0.5*(accH@vW2 + s*vb2) + 0.25*(s*in_i + accI)
__global__ __launch_bounds__(256) void k_x(
    const float* __restrict__ inp, const float* __restrict__ pos,
    const float* __restrict__ vW1, const float* __restrict__ vb1,
    const float* __restrict__ vg, const float* __restrict__ vbeta,
    const float* __restrict__ vW2, const float* __restrict__ vb2,
    const float* __restrict__ att, float* __restrict__ xout) {
    int i = blockIdx.x, b = blockIdx.y;
    int tid = threadIdx.x;
    int jsub = tid >> 3, dg = tid & 7;

    __shared__ float accH[32 * 128];
    __shared__ float accI[32 * 64];
    __shared__ float accS[32];

    float aH[16];
    float aI[8];
#pragma unroll
    for (int dd = 0; dd < 16; ++dd) aH[dd] = 0.f;
#pragma unroll
    for (int ff = 0; ff < 8; ++ff) aI[ff] = 0.f;
    float aS = 0.f;

    const float* pi = pos + (size_t)(b * N_ + i) * 3;
    float ax = pi[0], ay = pi[1], az = pi[2];

    for (int jc = 0; jc < 12; ++jc) {
        int j = jc * 32 + jsub;
        const float* pj = pos + (size_t)(b * N_ + j) * 3;
        float bx = pj[0], by = pj[1], bz = pj[2];
        float dotv = ax * bx + ay * by + az * bz;
        float cx = ay * bz - az * by;
        float cy = az * bx - ax * bz;
        float cz = ax * by - ay * bx;
        float cn = sqrtf(cx * cx + cy * cy + cz * cz);
        float a = att[(size_t)(b * N_ + i) * N_ + j];

        float h[16];
        float s1 = 0.f, s2 = 0.f;
#pragma unroll
        for (int dd = 0; dd < 16; ++dd) {
            int d = dg * 16 + dd;
            float v = fmaf(dotv, vW1[d], fmaf(cn, vW1[H_ + d], vb1[d]));
            h[dd] = v;
            s1 += v;
            s2 = fmaf(v, v, s2);
        }
        s1 += __shfl_xor(s1, 1); s1 += __shfl_xor(s1, 2); s1 += __shfl_xor(s1, 4);
        s2 += __shfl_xor(s2, 1); s2 += __shfl_xor(s2, 2); s2 += __shfl_xor(s2, 4);
        float mu = s1 * (1.f / 128.f);
        float var = s2 * (1.f / 128.f) - mu * mu;
        float rstd = rsqrtf(var + LN_EPS);
#pragma unroll
        for (int dd = 0; dd < 16; ++dd) {
            int d = dg * 16 + dd;
            float v = fmaf((h[dd] - mu) * rstd, vg[d], vbeta[d]);
            aH[dd] = fmaf(a, fmaxf(v, 0.f), aH[dd]);
        }
#pragma unroll
        for (int ff = 0; ff < 8; ++ff) {
            int f = dg * 8 + ff;
            aI[ff] = fmaf(a, inp[(size_t)(b * N_ + j) * F_ + f], aI[ff]);
        }
        if (dg == 0) aS += a;
    }

#pragma unroll
    for (int dd = 0; dd < 16; ++dd) accH[jsub * 128 + dg * 16 + dd] = aH[dd];
#pragma unroll
    for (int ff = 0; ff < 8; ++ff) accI[jsub * 64 + dg * 8 + ff] = aI[ff];
    if (dg == 0) accS[jsub] = aS;
    __syncthreads();

    for (int st = 16; st > 0; st >>= 1) {
        if (jsub < st) {
#pragma unroll
            for (int dd = 0; dd < 16; ++dd)
                accH[jsub * 128 + dg * 16 + dd] += accH[(jsub + st) * 128 + dg * 16 + dd];
#pragma unroll
            for (int ff = 0; ff < 8; ++ff)
                accI[jsub * 64 + dg * 8 + ff] += accI[(jsub + st) * 64 + dg * 8 + ff];
            if (dg == 0) accS[jsub] += accS[jsub + st];
        }
        __syncthreads();
    }

    if (tid < F_) {
        int f = tid;
        float s = accS[0];
        float xv = 0.f;
#pragma unroll
        for (int d = 0; d < H_; ++d) xv = fmaf(accH[d], vW2[d * F_ + f], xv);
        float r = 0.5f * (xv + s * vb2[f]) +
                  0.25f * (s * inp[(size_t)(b * N_ + i) * F_ + f] + accI[f]);
        xout[(size_t)(b * N_ + i) * F_ + f] = r;
    }
}

// -------------------- launch --------------------

extern "C" void kernel_launch(void* const* d_in, const int* in_sizes, int n_in,
                              void* d_out, int out_size, void* d_ws, size_t ws_size,
                              hipStream_t stream) {
    const float* inp   = (const float*)d_in[0];
    const float* pos   = (const float*)d_in[1];
    const float* vW1   = (const float*)d_in[2];
    const float* vb1   = (const float*)d_in[3];
    const float* vg    = (const float*)d_in[4];
    const float* vbeta = (const float*)d_in[5];
    const float* vW2   = (const float*)d_in[6];
    const float* vb2   = (const float*)d_in[7];
    const float* sW1   = (const float*)d_in[8];
    const float* sb1   = (const float*)d_in[9];
    const float* sW2   = (const float*)d_in[10];
    const float* sb2   = (const float*)d_in[11];

    float* xout   = (float*)d_out;                 // B*N*F
    float* attout = xout + B_ * N_ * F_;           // B*N*N (scores -> att in place)

    float* W2p  = (float*)d_ws;                    // 128*128
    float* t    = W2p + H_ * H_;                   // B*N*128
    float* pmax = t + B_ * N_ * H_;                // B*72
    float* psum = pmax + B_ * NCHUNK;              // B*72

    k_prep_w2p<<<64, 256, 0, stream>>>(vW2, sW1, W2p);
    k_prep_t<<<B_ * N_, 128, 0, stream>>>(inp, sW1, vb2, sb1, t);
    k_scores<<<dim3(N_ / 8, N_ / 8, B_), 256, 0, stream>>>(
        pos, vW1, vb1, vg, vbeta, W2p, t, sW2, sb2, attout);
    k_pmax<<<dim3(NCHUNK, B_), 256, 0, stream>>>(attout, pmax);
    k_psum<<<dim3(NCHUNK, B_), 256, 0, stream>>>(attout, pmax, psum);
    k_att<<<dim3(N_, B_), 384, 0, stream>>>(attout, pmax, psum);
    k_x<<<dim3(N_, B_), 256, 0, stream>>>(inp, pos, vW1, vb1, vg, vbeta, vW2, vb2,
                                          attout, xout);
}

// Round 4
// 465.192 us; speedup vs baseline: 1.4340x; 1.4340x over previous
//
#include <hip/hip_runtime.h>
#include <hip/hip_bf16.h>
#include <math.h>

#define B_ 8
#define N_ 384
#define F_ 64
#define H_ 128
#define LN_EPS 1e-5f
#define NCHUNK 72          // N_*N_ / 2048

typedef _Float16 f16;
typedef f16 f16x8 __attribute__((ext_vector_type(8)));
typedef float f32x4v __attribute__((ext_vector_type(4)));

// -------------------- setup kernels --------------------

// W2hT[n][k] = fp16( 0.5 * sum_f vW2[k,f] * sW1[f,n] )   (128x128, TRANSPOSED for MFMA A)
__global__ void k_prep_w2p(const float* __restrict__ vW2, const float* __restrict__ sW1,
                           unsigned short* __restrict__ W2hT) {
    int idx = blockIdx.x * 256 + threadIdx.x;   // 0..16383
    int k = idx >> 7, n = idx & 127;
    float acc = 0.f;
#pragma unroll
    for (int f = 0; f < F_; ++f) acc = fmaf(vW2[k * F_ + f], sW1[f * H_ + n], acc);
    f16 hv = (f16)(0.5f * acc);
    W2hT[n * H_ + k] = *reinterpret_cast<unsigned short*>(&hv);
}

// t[row][n] = sum_f (0.25*(in[row,f]+vb2[f])) * sW1[f,n] + 0.5*sb1[n]
__global__ void k_prep_t(const float* __restrict__ inp, const float* __restrict__ sW1,
                         const float* __restrict__ vb2, const float* __restrict__ sb1,
                         float* __restrict__ t) {
    int row = blockIdx.x;
    int n = threadIdx.x;
    float acc = 0.f;
#pragma unroll
    for (int f = 0; f < F_; ++f)
        acc = fmaf(0.25f * (inp[row * F_ + f] + vb2[f]), sW1[f * H_ + n], acc);
    t[row * H_ + n] = acc + 0.5f * sb1[n];
}

// -------------------- phase 1: scores (fp16 MFMA) --------------------
// Block: 8x8 pair tile (64 pairs), 256 threads = 4 waves.
// Phase A: relu(LN(inv@vW1+vb1)) -> fp16 LDS rhtb[pair][k], XOR-swizzled.
// Stage:  W2hT (W'^T fp16) -> LDS, XOR-swizzled.
// GEMM:   u^T[n][pair] = W'^T @ relu_h^T via mfma_f32_16x16x32_f16.
//         wave w owns pair-frag w (16 pairs); acc[8] frags cover n=0..127.
// Phase C: u + t_i + t_j, relu, dot sW2, 2-shuffle reduce -> score.
#define W2HT_OFF 0
#define RHT_OFF  32768
__global__ __launch_bounds__(256, 3) void k_scores(
    const float* __restrict__ pos, const float* __restrict__ vW1,
    const float* __restrict__ vb1, const float* __restrict__ vg,
    const float* __restrict__ vbeta, const unsigned short* __restrict__ W2hT,
    const float* __restrict__ t, const float* __restrict__ sW2,
    const float* __restrict__ sb2, float* __restrict__ scores) {
    __shared__ __align__(16) char smem[49152];   // 32KB W2hT + 16KB rhtb (t_lds overlays rhtb)

    const int tid = threadIdx.x;
    const int b = blockIdx.z;
    const int i0 = blockIdx.y * 8, j0 = blockIdx.x * 8;

    // ---- stage W' (transposed fp16) into LDS, swizzled ----
#pragma unroll
    for (int s = 0; s < 8; ++s) {
        int idx = tid + s * 256;                 // 0..2047 16B chunks
        int n = idx >> 4, c = idx & 15;
        uint4 v = *(const uint4*)(W2hT + n * H_ + c * 8);
        *(uint4*)(smem + W2HT_OFF + ((n * 256 + c * 16) ^ ((n & 7) << 4))) = v;
    }

    // ---- Phase A: 4 lanes per pair, each owns 32 of 128 dims ----
    {
        const int p = tid >> 2, l = tid & 3;
        const int i = i0 + (p >> 3), j = j0 + (p & 7);
        const float* pi = pos + (size_t)(b * N_ + i) * 3;
        const float* pj = pos + (size_t)(b * N_ + j) * 3;
        float ax = pi[0], ay = pi[1], az = pi[2];
        float bx = pj[0], by = pj[1], bz = pj[2];
        float dotv = ax * bx + ay * by + az * bz;
        float cx = ay * bz - az * by;
        float cy = az * bx - ax * bz;
        float cz = ax * by - ay * bx;
        float cn = sqrtf(cx * cx + cy * cy + cz * cz);

        float h[32];
        float s1 = 0.f, s2 = 0.f;
        const int d0 = l * 32;
#pragma unroll
        for (int s = 0; s < 8; ++s) {
            float4 wa = *(const float4*)(vW1 + d0 + s * 4);
            float4 wb = *(const float4*)(vW1 + H_ + d0 + s * 4);
            float4 bv = *(const float4*)(vb1 + d0 + s * 4);
            float v;
            v = fmaf(dotv, wa.x, fmaf(cn, wb.x, bv.x)); h[s*4+0] = v; s1 += v; s2 = fmaf(v, v, s2);
            v = fmaf(dotv, wa.y, fmaf(cn, wb.y, bv.y)); h[s*4+1] = v; s1 += v; s2 = fmaf(v, v, s2);
            v = fmaf(dotv, wa.z, fmaf(cn, wb.z, bv.z)); h[s*4+2] = v; s1 += v; s2 = fmaf(v, v, s2);
            v = fmaf(dotv, wa.w, fmaf(cn, wb.w, bv.w)); h[s*4+3] = v; s1 += v; s2 = fmaf(v, v, s2);
        }
        s1 += __shfl_xor(s1, 1); s1 += __shfl_xor(s1, 2);
        s2 += __shfl_xor(s2, 1); s2 += __shfl_xor(s2, 2);
        float mu = s1 * (1.f / 128.f);
        float var = s2 * (1.f / 128.f) - mu * mu;
        float rstd = rsqrtf(var + LN_EPS);
        const int psw = (p & 7) << 4;
#pragma unroll
        for (int s = 0; s < 4; ++s) {
            float4 g0 = *(const float4*)(vg + d0 + s * 8);
            float4 g1 = *(const float4*)(vg + d0 + s * 8 + 4);
            float4 e0 = *(const float4*)(vbeta + d0 + s * 8);
            float4 e1 = *(const float4*)(vbeta + d0 + s * 8 + 4);
            f16x8 pk;
            pk[0] = (f16)fmaxf(fmaf((h[s*8+0] - mu) * rstd, g0.x, e0.x), 0.f);
            pk[1] = (f16)fmaxf(fmaf((h[s*8+1] - mu) * rstd, g0.y, e0.y), 0.f);
            pk[2] = (f16)fmaxf(fmaf((h[s*8+2] - mu) * rstd, g0.z, e0.z), 0.f);
            pk[3] = (f16)fmaxf(fmaf((h[s*8+3] - mu) * rstd, g0.w, e0.w), 0.f);
            pk[4] = (f16)fmaxf(fmaf((h[s*8+4] - mu) * rstd, g1.x, e1.x), 0.f);
            pk[5] = (f16)fmaxf(fmaf((h[s*8+5] - mu) * rstd, g1.y, e1.y), 0.f);
            pk[6] = (f16)fmaxf(fmaf((h[s*8+6] - mu) * rstd, g1.z, e1.z), 0.f);
            pk[7] = (f16)fmaxf(fmaf((h[s*8+7] - mu) * rstd, g1.w, e1.w), 0.f);
            *(f16x8*)(smem + RHT_OFF + ((p * 256 + l * 64 + s * 16) ^ psw)) = pk;
        }
    }
    __syncthreads();

    // ---- GEMM: acc[mf] = sum_k W'^T-frag(mf) * rht^T-frag(pair) ----
    const int wv = tid >> 6;           // wave 0..3
    const int ln = tid & 15;
    const int h4 = (tid >> 4) & 3;
    const int pr = wv * 16 + ln;       // this lane's pair (output column)
    const int prsw = (pr & 7) << 4;
    const int nsw = (ln & 7) << 4;

    f32x4v acc[8];
#pragma unroll
    for (int mf = 0; mf < 8; ++mf) acc[mf] = (f32x4v){0.f, 0.f, 0.f, 0.f};

#pragma unroll
    for (int kc = 0; kc < 4; ++kc) {
        const int kb = kc * 64 + h4 * 16;    // byte offset of k-chunk
        f16x8 bF = *(const f16x8*)(smem + RHT_OFF + ((pr * 256 + kb) ^ prsw));
#pragma unroll
        for (int mf = 0; mf < 8; ++mf) {
            const int n = mf * 16 + ln;
            f16x8 aF = *(const f16x8*)(smem + W2HT_OFF + ((n * 256 + kb) ^ nsw));
            acc[mf] = __builtin_amdgcn_mfma_f32_16x16x32_f16(aF, bF, acc[mf], 0, 0, 0);
        }
    }
    __syncthreads();

    // ---- stage t rows (8 i-rows, 8 j-rows) into rhtb region, swizzled ----
#pragma unroll
    for (int s = 0; s < 2; ++s) {
        int idx = tid + s * 256;             // 0..511 float4 chunks
        int r = idx >> 5, c4 = idx & 31;
        int row = (r < 8) ? (i0 + r) : (j0 + r - 8);
        uint4 v = *(const uint4*)(t + (size_t)(b * N_ + row) * H_ + c4 * 4);
        *(uint4*)(smem + RHT_OFF + ((r * 512 + c4 * 16) ^ ((r & 7) << 4))) = v;
    }
    __syncthreads();

    // ---- Phase C: u + t_i + t_j, relu, dot sW2, reduce over 4 h-lanes ----
    const int ri = pr >> 3;          // local i row (0..7)
    const int rj = 8 + (pr & 7);     // local j row (8..15)
    const int risw = (ri & 7) << 4;
    const int rjsw = (rj & 7) << 4;
    float part = 0.f;
#pragma unroll
    for (int mf = 0; mf < 8; ++mf) {
        const int cb = mf * 64 + h4 * 16;    // byte col offset = (16mf+4h4)*4
        float4 ti = *(const float4*)(smem + RHT_OFF + ((ri * 512 + cb) ^ risw));
        float4 tj = *(const float4*)(smem + RHT_OFF + ((rj * 512 + cb) ^ rjsw));
        float4 sw = *(const float4*)(sW2 + mf * 16 + h4 * 4);
        f32x4v a = acc[mf];
        part += fmaxf(a[0] + ti.x + tj.x, 0.f) * sw.x;
        part += fmaxf(a[1] + ti.y + tj.y, 0.f) * sw.y;
        part += fmaxf(a[2] + ti.z + tj.z, 0.f) * sw.z;
        part += fmaxf(a[3] + ti.w + tj.w, 0.f) * sw.w;
    }
    part += __shfl_xor(part, 16);
    part += __shfl_xor(part, 32);
    if (h4 == 0) {
        scores[(size_t)(b * N_ + i0 + (pr >> 3)) * N_ + j0 + (pr & 7)] = part + sb2[0];
    }
}

// -------------------- softmax reductions (deterministic trees) --------------------

__global__ void k_pmax(const float* __restrict__ scores, float* __restrict__ pmax) {
    int c = blockIdx.x, b = blockIdx.y;
    int tid = threadIdx.x;
    size_t base = (size_t)b * N_ * N_ + (size_t)c * 2048;
    float m = -1e30f;
#pragma unroll
    for (int s = 0; s < 8; ++s) m = fmaxf(m, scores[base + s * 256 + tid]);
    __shared__ float red[256];
    red[tid] = m;
    __syncthreads();
    for (int st = 128; st > 0; st >>= 1) {
        if (tid < st) red[tid] = fmaxf(red[tid], red[tid + st]);
        __syncthreads();
    }
    if (tid == 0) pmax[b * NCHUNK + c] = red[0];
}

__global__ void k_psum(const float* __restrict__ scores, const float* __restrict__ pmax,
                       float* __restrict__ psum) {
    int c = blockIdx.x, b = blockIdx.y;
    int tid = threadIdx.x;
    __shared__ float gm;
    __shared__ float red[256];
    if (tid == 0) {
        float m = -1e30f;
        for (int k = 0; k < NCHUNK; ++k) m = fmaxf(m, pmax[b * NCHUNK + k]);
        gm = m;
    }
    __syncthreads();
    size_t base = (size_t)b * N_ * N_ + (size_t)c * 2048;
    float s = 0.f;
#pragma unroll
    for (int k = 0; k < 8; ++k) s += expf(scores[base + k * 256 + tid] - gm);
    red[tid] = s;
    __syncthreads();
    for (int st = 128; st > 0; st >>= 1) {
        if (tid < st) red[tid] += red[tid + st];
        __syncthreads();
    }
    if (tid == 0) psum[b * NCHUNK + c] = red[0];
}

// normalize scores -> att in place (one block per (b,i) row)
__global__ void k_att(float* __restrict__ scores, const float* __restrict__ pmax,
                      const float* __restrict__ psum) {
    int i = blockIdx.x, b = blockIdx.y;
    int tid = threadIdx.x;   // 384
    __shared__ float gm, gs;
    if (tid == 0) {
        float m = -1e30f;
        for (int k = 0; k < NCHUNK; ++k) m = fmaxf(m, pmax[b * NCHUNK + k]);
        gm = m;
    } else if (tid == 1) {
        float s = 0.f;
        for (int k = 0; k < NCHUNK; ++k) s += psum[b * NCHUNK + k];
        gs = s;
    }
    __syncthreads();
    size_t idx = (size_t)(b * N_ + i) * N_ + tid;
    scores[idx] = expf(scores[idx] - gm) / gs;
}

// -------------------- phase 2: x --------------------
// One block per (b,i). Recompute relu_h fp32; accH = sum att*relu_h, accI = sum att*in_j,
// s = sum att. x = 0.5*(accH@vW2 + s*vb2) + 0.25*(s*in_i + accI)
__global__ __launch_bounds__(256) void k_x(
    const float* __restrict__ inp, const float* __restrict__ pos,
    const float* __restrict__ vW1, const float* __restrict__ vb1,
    const float* __restrict__ vg, const float* __restrict__ vbeta,
    const float* __restrict__ vW2, const float* __restrict__ vb2,
    const float* __restrict__ att, float* __restrict__ xout) {
    int i = blockIdx.x, b = blockIdx.y;
    int tid = threadIdx.x;
    int jsub = tid >> 3, dg = tid & 7;

    __shared__ float accH[32 * 128];
    __shared__ float accI[32 * 64];
    __shared__ float accS[32];

    float aH[16];
    float aI[8];
#pragma unroll
    for (int dd = 0; dd < 16; ++dd) aH[dd] = 0.f;
#pragma unroll
    for (int ff = 0; ff < 8; ++ff) aI[ff] = 0.f;
    float aS = 0.f;

    const float* pi = pos + (size_t)(b * N_ + i) * 3;
    float ax = pi[0], ay = pi[1], az = pi[2];

    for (int jc = 0; jc < 12; ++jc) {
        int j = jc * 32 + jsub;
        const float* pj = pos + (size_t)(b * N_ + j) * 3;
        float bx = pj[0], by = pj[1], bz = pj[2];
        float dotv = ax * bx + ay * by + az * bz;
        float cx = ay * bz - az * by;
        float cy = az * bx - ax * bz;
        float cz = ax * by - ay * bx;
        float cn = sqrtf(cx * cx + cy * cy + cz * cz);
        float a = att[(size_t)(b * N_ + i) * N_ + j];

        float h[16];
        float s1 = 0.f, s2 = 0.f;
#pragma unroll
        for (int dd = 0; dd < 16; ++dd) {
            int d = dg * 16 + dd;
            float v = fmaf(dotv, vW1[d], fmaf(cn, vW1[H_ + d], vb1[d]));
            h[dd] = v;
            s1 += v;
            s2 = fmaf(v, v, s2);
        }
        s1 += __shfl_xor(s1, 1); s1 += __shfl_xor(s1, 2); s1 += __shfl_xor(s1, 4);
        s2 += __shfl_xor(s2, 1); s2 += __shfl_xor(s2, 2); s2 += __shfl_xor(s2, 4);
        float mu = s1 * (1.f / 128.f);
        float var = s2 * (1.f / 128.f) - mu * mu;
        float rstd = rsqrtf(var + LN_EPS);
#pragma unroll
        for (int dd = 0; dd < 16; ++dd) {
            int d = dg * 16 + dd;
            float v = fmaf((h[dd] - mu) * rstd, vg[d], vbeta[d]);
            aH[dd] = fmaf(a, fmaxf(v, 0.f), aH[dd]);
        }
#pragma unroll
        for (int ff = 0; ff < 8; ++ff) {
            int f = dg * 8 + ff;
            aI[ff] = fmaf(a, inp[(size_t)(b * N_ + j) * F_ + f], aI[ff]);
        }
        if (dg == 0) aS += a;
    }

#pragma unroll
    for (int dd = 0; dd < 16; ++dd) accH[jsub * 128 + dg * 16 + dd] = aH[dd];
#pragma unroll
    for (int ff = 0; ff < 8; ++ff) accI[jsub * 64 + dg * 8 + ff] = aI[ff];
    if (dg == 0) accS[jsub] = aS;
    __syncthreads();

    for (int st = 16; st > 0; st >>= 1) {
        if (jsub < st) {
#pragma unroll
            for (int dd = 0; dd < 16; ++dd)
                accH[jsub * 128 + dg * 16 + dd] += accH[(jsub + st) * 128 + dg * 16 + dd];
#pragma unroll
            for (int ff = 0; ff < 8; ++ff)
                accI[jsub * 64 + dg * 8 + ff] += accI[(jsub + st) * 64 + dg * 8 + ff];
            if (dg == 0) accS[jsub] += accS[jsub + st];
        }
        __syncthreads();
    }

    if (tid < F_) {
        int f = tid;
        float s = accS[0];
        float xv = 0.f;
#pragma unroll
        for (int d = 0; d < H_; ++d) xv = fmaf(accH[d], vW2[d * F_ + f], xv);
        float r = 0.5f * (xv + s * vb2[f]) +
                  0.25f * (s * inp[(size_t)(b * N_ + i) * F_ + f] + accI[f]);
        xout[(size_t)(b * N_ + i) * F_ + f] = r;
    }
}

// -------------------- launch --------------------

extern "C" void kernel_launch(void* const* d_in, const int* in_sizes, int n_in,
                              void* d_out, int out_size, void* d_ws, size_t ws_size,
                              hipStream_t stream) {
    const float* inp   = (const float*)d_in[0];
    const float* pos   = (const float*)d_in[1];
    const float* vW1   = (const float*)d_in[2];
    const float* vb1   = (const float*)d_in[3];
    const float* vg    = (const float*)d_in[4];
    const float* vbeta = (const float*)d_in[5];
    const float* vW2   = (const float*)d_in[6];
    const float* vb2   = (const float*)d_in[7];
    const float* sW1   = (const float*)d_in[8];
    const float* sb1   = (const float*)d_in[9];
    const float* sW2   = (const float*)d_in[10];
    const float* sb2   = (const float*)d_in[11];

    float* xout   = (float*)d_out;                 // B*N*F
    float* attout = xout + B_ * N_ * F_;           // B*N*N (scores -> att in place)

    unsigned short* W2hT = (unsigned short*)d_ws;          // 128*128 fp16 (32KB)
    float* t    = (float*)((char*)d_ws + 32768);           // B*N*128 fp32
    float* pmax = t + B_ * N_ * H_;                        // B*72
    float* psum = pmax + B_ * NCHUNK;                      // B*72

    k_prep_w2p<<<64, 256, 0, stream>>>(vW2, sW1, W2hT);
    k_prep_t<<<B_ * N_, 128, 0, stream>>>(inp, sW1, vb2, sb1, t);
    k_scores<<<dim3(N_ / 8, N_ / 8, B_), 256, 0, stream>>>(
        pos, vW1, vb1, vg, vbeta, W2hT, t, sW2, sb2, attout);
    k_pmax<<<dim3(NCHUNK, B_), 256, 0, stream>>>(attout, pmax);
    k_psum<<<dim3(NCHUNK, B_), 256, 0, stream>>>(attout, pmax, psum);
    k_att<<<dim3(N_, B_), 384, 0, stream>>>(attout, pmax, psum);
    k_x<<<dim3(N_, B_), 256, 0, stream>>>(inp, pos, vW1, vb1, vg, vbeta, vW2, vb2,
                                          attout, xout);
}